// Round 5
// baseline (531.296 us; speedup 1.0000x reference)
//
#include <hip/hip_runtime.h>
#include <cstdint>
#include <cstddef>

#define N_NODES 50000
#define N_EDGES 500000
#define N_GRAPHS 256
#define D_IN 768
#define D_H1 256
#define D_H2 128

typedef __attribute__((ext_vector_type(8))) __bf16 bf16x8;
typedef __attribute__((ext_vector_type(4))) float f32x4;

__device__ __forceinline__ float bf2f(uint32_t u) {
    union { uint32_t i; float f; } v; v.i = u << 16; return v.f;
}
__device__ __forceinline__ uint32_t f2bf(float f) {
    union { float f; uint32_t i; } v; v.f = f;
    uint32_t u = v.i;
    return (u + 0x7FFFu + ((u >> 16) & 1u)) >> 16;
}

// ---- pack helper: one 64-chunk of fragment-tile layout from row-major fp32 ----
__device__ __forceinline__ void pack_chunk(const float* __restrict__ src_row,
                                           uint16_t* __restrict__ out, int c) {
    float4 u = *(const float4*)src_row, v = *(const float4*)(src_row + 4);
    uint4 o;
    o.x = f2bf(u.x) | (f2bf(u.y) << 16);
    o.y = f2bf(u.z) | (f2bf(u.w) << 16);
    o.z = f2bf(v.x) | (f2bf(v.y) << 16);
    o.w = f2bf(v.z) | (f2bf(v.w) << 16);
    *(uint4*)(out + (size_t)c * 8) = o;
}

// ---- combo: packA(x) || hist || packW1 || packW2, grid-partitioned ----
#define PA_BLK 18750   // 3125 mt * 24 kt * 64 / 256
#define HI_BLK 1954    // ceil(500000/256)
#define PW1_BLK 192    // 32*24*64/256
#define PW2_BLK 32     // 16*8*64/256
__global__ __launch_bounds__(256) void k_combo(
    const float* __restrict__ x, uint16_t* __restrict__ xp,
    const int* __restrict__ dst, int* __restrict__ deg,
    const float* __restrict__ W1l, const float* __restrict__ W1r, uint16_t* __restrict__ W1p,
    const float* __restrict__ W2l, const float* __restrict__ W2r, uint16_t* __restrict__ W2p)
{
    int b = blockIdx.x, tid = threadIdx.x;
    if (b < PA_BLK) {
        int c = b * 256 + tid;                    // < 4,800,000 exactly
        int l = c & 63, t = c >> 6;
        int kt = t % 24, mt = t / 24;
        int fr = l & 15, fq = l >> 4;
        pack_chunk(x + (size_t)(mt * 16 + fr) * 768 + kt * 32 + fq * 8, xp, c);
    } else if (b < PA_BLK + HI_BLK) {
        int e = (b - PA_BLK) * 256 + tid;
        if (e < N_EDGES) atomicAdd(&deg[dst[e]], 1);
    } else if (b < PA_BLK + HI_BLK + PW1_BLK) {
        int c = (b - PA_BLK - HI_BLK) * 256 + tid;  // < 49152 exactly
        int l = c & 63, t = c >> 6;
        int kt = t % 24, mt = t / 24;
        int fr = l & 15, fq = l >> 4;
        int row = mt * 16 + fr;
        const float* src = (row < 256) ? (W1l + (size_t)row * 768)
                                       : (W1r + (size_t)(row - 256) * 768);
        pack_chunk(src + kt * 32 + fq * 8, W1p, c);
    } else {
        int c = (b - PA_BLK - HI_BLK - PW1_BLK) * 256 + tid;  // < 8192 exactly
        int l = c & 63, t = c >> 6;
        int kt = t % 8, mt = t / 8;
        int fr = l & 15, fq = l >> 4;
        int row = mt * 16 + fr;
        const float* src = (row < 128) ? (W2l + (size_t)row * 256)
                                       : (W2r + (size_t)(row - 128) * 256);
        pack_chunk(src + kt * 32 + fq * 8, W2p, c);
    }
}

// ---- single-pass exclusive scan, decoupled lookback (196 blocks, all co-resident) ----
__global__ __launch_bounds__(256) void k_scan(
    const int* __restrict__ deg, unsigned long long* __restrict__ desc,
    int* __restrict__ row_start, float* __restrict__ deg_inv, int n)
{
    __shared__ int buf[256];
    __shared__ int s_prefix;
    int bid = blockIdx.x, t = threadIdx.x;
    int i = bid * 256 + t;
    int v = (i < n) ? deg[i] : 0;
    buf[t] = v; __syncthreads();
    for (int off = 1; off < 256; off <<= 1) {
        int u = (t >= off) ? buf[t - off] : 0;
        __syncthreads(); buf[t] += u; __syncthreads();
    }
    if (t == 0) {
        unsigned long long total = (unsigned long long)(unsigned)buf[255];
        __hip_atomic_store(&desc[bid], (1ull << 32) | total,
                           __ATOMIC_RELEASE, __HIP_MEMORY_SCOPE_AGENT);
        unsigned long long run = 0;
        for (int j = bid - 1; j >= 0; --j) {
            unsigned long long d;
            do {
                d = __hip_atomic_load(&desc[j], __ATOMIC_ACQUIRE, __HIP_MEMORY_SCOPE_AGENT);
            } while ((d >> 32) == 0);
            run += (d & 0xFFFFFFFFull);
            if ((d >> 32) == 2) break;
        }
        __hip_atomic_store(&desc[bid], (2ull << 32) | (run + total),
                           __ATOMIC_RELEASE, __HIP_MEMORY_SCOPE_AGENT);
        s_prefix = (int)run;
    }
    __syncthreads();
    int ex = s_prefix + buf[t] - v;
    if (i < n) {
        row_start[i] = ex;
        deg_inv[i] = (v > 0) ? (1.0f / (float)v) : 0.0f;
        if (i == n - 1) row_start[n] = ex + v;
    }
}

// ---------------- CSR fill ----------------
__global__ void k_fill(const int* __restrict__ src, const int* __restrict__ dst,
                       const int* __restrict__ row_start, int* __restrict__ cursor,
                       int* __restrict__ csr_src, int n) {
    int e = blockIdx.x * blockDim.x + threadIdx.x;
    if (e < n) {
        int d = dst[e];
        int pos = row_start[d] + atomicAdd(&cursor[d], 1);
        csr_src[pos] = src[e];
    }
}

// ---------------- barrier-free MFMA GEMM on fragment-packed operands ----------
__global__ __launch_bounds__(256, 2) void k_mgemm(
    const uint16_t* __restrict__ Ap, const uint16_t* __restrict__ Bp,
    uint16_t* __restrict__ C, int M, int N, int KT)
{
    const int tid = threadIdx.x;
    const int wave = tid >> 6, lane = tid & 63;
    const int fr = lane & 15, fq = lane >> 4;
    const int bn = blockIdx.x * 256, bm = blockIdx.y * 128;
    const int wm = (wave >> 1) * 64, wn = (wave & 1) * 128;
    const int mtiles = (M + 15) >> 4;

    const bf16x8* ap[4];
    const bf16x8* bp[8];
    #pragma unroll
    for (int mi = 0; mi < 4; ++mi) {
        int mt = ((bm + wm) >> 4) + mi;
        if (mt > mtiles - 1) mt = mtiles - 1;
        ap[mi] = (const bf16x8*)Ap + (size_t)mt * KT * 64 + lane;
    }
    #pragma unroll
    for (int ni = 0; ni < 8; ++ni) {
        int nt = ((bn + wn) >> 4) + ni;
        bp[ni] = (const bf16x8*)Bp + (size_t)nt * KT * 64 + lane;
    }

    f32x4 acc[4][8] = {};
    bf16x8 a0[4], b0[8], a1[4], b1[8];

    auto lA = [&](int kt, bf16x8* d) {
        #pragma unroll
        for (int mi = 0; mi < 4; ++mi) d[mi] = ap[mi][kt * 64];
    };
    auto lB = [&](int kt, bf16x8* d) {
        #pragma unroll
        for (int ni = 0; ni < 8; ++ni) d[ni] = bp[ni][kt * 64];
    };
    auto step = [&](bf16x8* a, bf16x8* b) {
        #pragma unroll
        for (int mi = 0; mi < 4; ++mi)
            #pragma unroll
            for (int ni = 0; ni < 8; ++ni)
                acc[mi][ni] = __builtin_amdgcn_mfma_f32_16x16x32_bf16(
                    a[mi], b[ni], acc[mi][ni], 0, 0, 0);
    };

    lA(0, a0); lB(0, b0);
    for (int ks = 0; ks < KT; ks += 2) {
        lA(ks + 1, a1); lB(ks + 1, b1);
        step(a0, b0);
        if (ks + 2 < KT) { lA(ks + 2, a0); lB(ks + 2, b0); }
        step(a1, b1);
    }

    #pragma unroll
    for (int mi = 0; mi < 4; ++mi) {
        #pragma unroll
        for (int r = 0; r < 4; ++r) {
            int row = bm + wm + mi * 16 + fq * 4 + r;
            if (row >= M) continue;
            #pragma unroll
            for (int ni = 0; ni < 8; ++ni) {
                int col = bn + wn + ni * 16 + fr;
                C[(size_t)row * N + col] = (uint16_t)f2bf(acc[mi][ni][r]);
            }
        }
    }
}

// ---- fused aggregate layer1 -> packed h1 (half-wave per node) ----
__global__ __launch_bounds__(256) void k_agg1(
    const uint16_t* __restrict__ y, const int* __restrict__ row_start,
    const int* __restrict__ csr, const float* __restrict__ deg_inv,
    const float* __restrict__ bias, uint16_t* __restrict__ h1p)
{
    int node = blockIdx.x * 8 + (threadIdx.x >> 5);
    if (node >= N_NODES) return;
    int c = threadIdx.x & 31;
    int s = row_start[node], e = row_start[node + 1];
    float a[8] = {};
    int p = s;
    for (; p + 1 < e; p += 2) {
        uint4 t0 = *(const uint4*)(y + (size_t)csr[p] * 512 + c * 8);
        uint4 t1 = *(const uint4*)(y + (size_t)csr[p + 1] * 512 + c * 8);
        a[0] += bf2f(t0.x & 0xFFFF) + bf2f(t1.x & 0xFFFF);
        a[1] += bf2f(t0.x >> 16)    + bf2f(t1.x >> 16);
        a[2] += bf2f(t0.y & 0xFFFF) + bf2f(t1.y & 0xFFFF);
        a[3] += bf2f(t0.y >> 16)    + bf2f(t1.y >> 16);
        a[4] += bf2f(t0.z & 0xFFFF) + bf2f(t1.z & 0xFFFF);
        a[5] += bf2f(t0.z >> 16)    + bf2f(t1.z >> 16);
        a[6] += bf2f(t0.w & 0xFFFF) + bf2f(t1.w & 0xFFFF);
        a[7] += bf2f(t0.w >> 16)    + bf2f(t1.w >> 16);
    }
    if (p < e) {
        uint4 t0 = *(const uint4*)(y + (size_t)csr[p] * 512 + c * 8);
        a[0] += bf2f(t0.x & 0xFFFF); a[1] += bf2f(t0.x >> 16);
        a[2] += bf2f(t0.y & 0xFFFF); a[3] += bf2f(t0.y >> 16);
        a[4] += bf2f(t0.z & 0xFFFF); a[5] += bf2f(t0.z >> 16);
        a[6] += bf2f(t0.w & 0xFFFF); a[7] += bf2f(t0.w >> 16);
    }
    float w = deg_inv[node];
    uint4 tx = *(const uint4*)(y + (size_t)node * 512 + 256 + c * 8);
    float4 b0 = *(const float4*)(bias + c * 8);
    float4 b1 = *(const float4*)(bias + c * 8 + 4);
    float v0 = fmaxf(a[0] * w + bf2f(tx.x & 0xFFFF) + b0.x, 0.f);
    float v1 = fmaxf(a[1] * w + bf2f(tx.x >> 16)    + b0.y, 0.f);
    float v2 = fmaxf(a[2] * w + bf2f(tx.y & 0xFFFF) + b0.z, 0.f);
    float v3 = fmaxf(a[3] * w + bf2f(tx.y >> 16)    + b0.w, 0.f);
    float v4 = fmaxf(a[4] * w + bf2f(tx.z & 0xFFFF) + b1.x, 0.f);
    float v5 = fmaxf(a[5] * w + bf2f(tx.z >> 16)    + b1.y, 0.f);
    float v6 = fmaxf(a[6] * w + bf2f(tx.w & 0xFFFF) + b1.z, 0.f);
    float v7 = fmaxf(a[7] * w + bf2f(tx.w >> 16)    + b1.w, 0.f);
    uint4 o;
    o.x = f2bf(v0) | (f2bf(v1) << 16);
    o.y = f2bf(v2) | (f2bf(v3) << 16);
    o.z = f2bf(v4) | (f2bf(v5) << 16);
    o.w = f2bf(v6) | (f2bf(v7) << 16);
    uint32_t addr = (((node >> 4) * 8 + (c >> 2)) * 64 + (c & 3) * 16 + (node & 15));
    *(uint4*)(h1p + (size_t)addr * 8) = o;
}

// ---- fused aggregate layer2 + mean-pool accumulate (atomics into pooled sums) ----
__global__ __launch_bounds__(256) void k_agg2pool(
    const uint16_t* __restrict__ y, const int* __restrict__ row_start,
    const int* __restrict__ csr, const float* __restrict__ deg_inv,
    const float* __restrict__ bias, const int* __restrict__ batch,
    float* __restrict__ pooled)
{
    int node = blockIdx.x * 4 + (threadIdx.x >> 6);
    if (node >= N_NODES) return;
    int lane = threadIdx.x & 63;
    int s = row_start[node], e = row_start[node + 1];
    float a0 = 0.f, a1 = 0.f;
    int p = s;
    for (; p + 1 < e; p += 2) {
        uint32_t t0 = *(const uint32_t*)(y + (size_t)csr[p] * 256 + lane * 2);
        uint32_t t1 = *(const uint32_t*)(y + (size_t)csr[p + 1] * 256 + lane * 2);
        a0 += bf2f(t0 & 0xFFFF) + bf2f(t1 & 0xFFFF);
        a1 += bf2f(t0 >> 16)    + bf2f(t1 >> 16);
    }
    if (p < e) {
        uint32_t t0 = *(const uint32_t*)(y + (size_t)csr[p] * 256 + lane * 2);
        a0 += bf2f(t0 & 0xFFFF);
        a1 += bf2f(t0 >> 16);
    }
    float w = deg_inv[node];
    uint32_t tx = *(const uint32_t*)(y + (size_t)node * 256 + 128 + lane * 2);
    float2 b = *(const float2*)(bias + lane * 2);
    float h0 = fmaxf(a0 * w + bf2f(tx & 0xFFFF) + b.x, 0.f);
    float h1 = fmaxf(a1 * w + bf2f(tx >> 16)    + b.y, 0.f);
    int g = batch[node];
    atomicAdd(&pooled[g * 128 + lane * 2], h0);
    atomicAdd(&pooled[g * 128 + lane * 2 + 1], h1);
}

// ---- head: counts by binary search; (pooled/cnt)@W3^T+b3 -> @W4^T+b4 -> softmax ----
__global__ void k_head(const float* __restrict__ pooled, const int* __restrict__ batch,
                       const float* __restrict__ W3, const float* __restrict__ b3,
                       const float* __restrict__ W4, const float* __restrict__ b4,
                       float* __restrict__ out)
{
    int g = blockIdx.x;
    int j = threadIdx.x;  // 64
    __shared__ float p[128];
    __shared__ float hid[64];
    __shared__ float logit[2];
    __shared__ float s_inv;
    if (j == 0) {
        int lo = 0, hi = N_NODES;
        while (lo < hi) { int m = (lo + hi) >> 1; if (batch[m] < g) lo = m + 1; else hi = m; }
        int lo2 = lo, hi2 = N_NODES;
        while (lo2 < hi2) { int m = (lo2 + hi2) >> 1; if (batch[m] < g + 1) lo2 = m + 1; else hi2 = m; }
        int cnt = lo2 - lo;
        s_inv = 1.0f / (float)(cnt > 0 ? cnt : 1);
    }
    __syncthreads();
    p[j]      = pooled[g * 128 + j] * s_inv;
    p[j + 64] = pooled[g * 128 + 64 + j] * s_inv;
    __syncthreads();
    float s = b3[j];
    #pragma unroll 4
    for (int k = 0; k < 128; ++k) s = fmaf(p[k], W3[j * 128 + k], s);
    hid[j] = s;
    __syncthreads();
    if (j < 2) {
        float l = b4[j];
        for (int k = 0; k < 64; ++k) l = fmaf(hid[k], W4[j * 64 + k], l);
        logit[j] = l;
    }
    __syncthreads();
    if (j == 0) {
        float m = fmaxf(logit[0], logit[1]);
        float e0 = expf(logit[0] - m), e1 = expf(logit[1] - m);
        float inv = 1.0f / (e0 + e1);
        out[g * 2 + 0] = e0 * inv;
        out[g * 2 + 1] = e1 * inv;
    }
}

extern "C" void kernel_launch(void* const* d_in, const int* in_sizes, int n_in,
                              void* d_out, int out_size, void* d_ws, size_t ws_size,
                              hipStream_t stream)
{
    const float* x     = (const float*)d_in[0];
    const int*   ei    = (const int*)d_in[1];
    const int*   batch = (const int*)d_in[2];
    const float* W1l   = (const float*)d_in[3];
    const float* b1l   = (const float*)d_in[4];
    const float* W1r   = (const float*)d_in[5];
    const float* W2l   = (const float*)d_in[6];
    const float* b2l   = (const float*)d_in[7];
    const float* W2r   = (const float*)d_in[8];
    const float* W3    = (const float*)d_in[9];
    const float* b3    = (const float*)d_in[10];
    const float* W4    = (const float*)d_in[11];
    const float* b4    = (const float*)d_in[12];
    float* out = (float*)d_out;

    const int* e_src = ei;
    const int* e_dst = ei + N_EDGES;

    char* ws = (char*)d_ws;
    size_t off = 0;
    auto alloc = [&](size_t bytes) -> void* {
        void* p = ws + off;
        off = (off + bytes + 255) & ~(size_t)255;
        return p;
    };
    // --- zeroed region (one memset) ---
    int*      deg       = (int*)alloc((size_t)N_NODES * 4);
    int*      cursor    = (int*)alloc((size_t)N_NODES * 4);
    float*    pooled    = (float*)alloc((size_t)N_GRAPHS * D_H2 * 4);
    unsigned long long* desc = (unsigned long long*)alloc(196 * 8);
    size_t zero_span = off;
    // --- rest ---
    int*      row_start = (int*)alloc((size_t)(N_NODES + 1) * 4);
    int*      csr_src   = (int*)alloc((size_t)N_EDGES * 4);
    float*    deg_inv   = (float*)alloc((size_t)N_NODES * 4);
    uint16_t* W1p       = (uint16_t*)alloc((size_t)512 * 768 * 2);
    uint16_t* W2p       = (uint16_t*)alloc((size_t)256 * 256 * 2);
    uint16_t* xp        = (uint16_t*)alloc((size_t)N_NODES * D_IN * 2);  // 76.8 MB
    uint16_t* y1        = (uint16_t*)alloc((size_t)N_NODES * 512 * 2);   // 51.2 MB
    uint16_t* h1p       = (uint16_t*)alloc((size_t)N_NODES * 256 * 2);   // 25.6 MB

    uint16_t* y2 = xp;   // [h1l|h1r] row-major, 25.6 MB (xp dead after GEMM1)

    hipMemsetAsync(deg, 0, zero_span, stream);

    // 1. pack x/W1/W2 + degree histogram (independent, one launch)
    k_combo<<<PA_BLK + HI_BLK + PW1_BLK + PW2_BLK, 256, 0, stream>>>(
        x, xp, e_dst, deg, W1l, W1r, W1p, W2l, W2r, W2p);
    // 2. exclusive scan (decoupled lookback) + deg_inv
    k_scan<<<196, 256, 0, stream>>>(deg, desc, row_start, deg_inv, N_NODES);
    // 3. CSR fill
    k_fill<<<(N_EDGES + 255) / 256, 256, 0, stream>>>(e_src, e_dst, row_start, cursor, csr_src, N_EDGES);
    // 4. Layer 1 GEMM: y1 = x @ [W1l|W1r]^T  (M=50000, N=512, K=768)
    dim3 g1(2, (N_NODES + 127) / 128);
    k_mgemm<<<g1, 256, 0, stream>>>(xp, W1p, y1, N_NODES, 512, 24);
    // 5. aggregate + bias + relu -> packed h1
    k_agg1<<<(N_NODES + 7) / 8, 256, 0, stream>>>(y1, row_start, csr_src, deg_inv, b1l, h1p);
    // 6. Layer 2 GEMM: y2 = h1 @ [W2l|W2r]^T  (M=50000, N=256, K=256)
    dim3 g2(1, (N_NODES + 127) / 128);
    k_mgemm<<<g2, 256, 0, stream>>>(h1p, W2p, y2, N_NODES, 256, 8);
    // 7. aggregate + bias + relu + pool-accumulate
    k_agg2pool<<<(N_NODES + 3) / 4, 256, 0, stream>>>(y2, row_start, csr_src, deg_inv, b2l, batch, pooled);
    // 8. head
    k_head<<<N_GRAPHS, 64, 0, stream>>>(pooled, batch, W3, b3, W4, b4, out);
}